// Round 1
// baseline (561.883 us; speedup 1.0000x reference)
//
#include <hip/hip_runtime.h>

#define TT 1024
#define DD 32
#define HH 64

typedef __fp16 h2v __attribute__((ext_vector_type(2)));
typedef _Float16 f16x8 __attribute__((ext_vector_type(8)));
typedef float f32x4 __attribute__((ext_vector_type(4)));

struct __attribute__((aligned(16))) H4 { h2v p[4]; };

__device__ __forceinline__ h2v pk(float a, float b) {
    return __builtin_amdgcn_cvt_pkrtz(a, b);
}
__device__ __forceinline__ float fsig(float x) {
    float e = __builtin_amdgcn_exp2f(-1.4426950408889634f * x);
    return __builtin_amdgcn_rcpf(1.0f + e);
}
__device__ __forceinline__ float ftanh(float x) {
    float e = __builtin_amdgcn_exp2f(2.885390081777927f * x);
    return 1.0f - 2.0f * __builtin_amdgcn_rcpf(1.0f + e);
}
__device__ __forceinline__ float pick4(f32x4 c, bool s0, bool s1) {
    float lo = s0 ? c[1] : c[0];
    float hi = s0 ? c[3] : c[2];
    return s1 ? hi : lo;
}
__device__ __forceinline__ f16x8 load_afrag(const float* p) {
    float4 f0 = *(const float4*)p;
    float4 f1 = *(const float4*)(p + 4);
    H4 t;
    t.p[0] = pk(f0.x, f0.y); t.p[1] = pk(f0.z, f0.w);
    t.p[2] = pk(f1.x, f1.y); t.p[3] = pk(f1.z, f1.w);
    return __builtin_bit_cast(f16x8, t);
}
#define MFMA16(A, B, C) __builtin_amdgcn_mfma_f32_16x16x32_f16(A, B, C, 0, 0, 0)

// ---------------------------------------------------------------------------
// R17: stale/fresh split of every LSTM cell across the barrier.
//  - L2 runs TWO steps behind L1. Each cell's matvec is split:
//      PRE  (before barrier, stale operands): L1: bias + W_ih*x(t+1)
//                                             L2: bias + W_ih_l1*h1(t-1)
//      POST (after barrier, fresh operands):  L1: += W_hh*h1(t-1)  -> act
//                                             L2: += W_hh_l1*h2(t-3) -> act
//    Partial accumulators carried in registers across the barrier (Ca/Cb
//    alternate, 4x-unrolled loop makes the alternation + slot indices
//    compile-time).
//  - LDS: 4-slot time ring [4][640 f16]: x @ +0, h1 @ +128, h2 @ +384.
//    Writers at iter t: h1->slot t&3, h2->slot (t-2)&3, x->slot (t+2)&3.
//    Readers: h1 (t-1)&3, h2 (t-3)&3, x (t+1)&3.  No same-iter collisions;
//    every cross-wave value crosses exactly one __syncthreads.
//  - Bias folded into MFMA C-in (per-reg bias vectors bv0..bv3).
//  - x stager moved wave7 -> wave0 (load balance: L1 waves are lighter).
// Post-barrier burst: 16 MFMAs/SIMD (was 28), chain depth 2 (was 4),
// 16 ds_read_b128/CU (was 28).
// ---------------------------------------------------------------------------
__global__ __launch_bounds__(512) void lstm2_b4(
    const float* __restrict__ x,
    const float* __restrict__ w_ih_l0, const float* __restrict__ w_hh_l0,
    const float* __restrict__ b_ih_l0, const float* __restrict__ b_hh_l0,
    const float* __restrict__ w_ih_l1, const float* __restrict__ w_hh_l1,
    const float* __restrict__ b_ih_l1, const float* __restrict__ b_hh_l1,
    const float* __restrict__ w_fc,   const float* __restrict__ b_fc,
    float* __restrict__ out)
{
    const int bbase = blockIdx.x * 4;
    const int tid  = threadIdx.x;
    const int wave = tid >> 6;
    const int lane = tid & 63;
    const bool isL1 = wave < 4;
    const int js   = wave & 3;
    const int quad = lane >> 4;
    const int bb   = lane & 3;
    const int rsel = (lane >> 2) & 3;
    const int jj   = js*16 + quad*4 + rsel;
    const int mrow = lane & 15;

    __shared__ __attribute__((aligned(16))) __fp16 buf[2560];  // [4 slots][640]

    {   // zero-init 1280 ints = 2560 f16
        int* bi = (int*)buf;
        bi[tid] = 0;
        bi[512 + tid] = 0;
        if (tid < 256) bi[1024 + tid] = 0;
    }

    // ---- A fragments (weights), per-reg bias vectors ----
    f16x8 A[16];
    f32x4 bv0, bv1, bv2, bv3;
    if (isL1) {
        #pragma unroll
        for (int q = 0; q < 4; ++q) {
            const int g = q*64 + js*16 + mrow;
            A[q*3 + 0] = load_afrag(w_ih_l0 + (size_t)g*DD + quad*8);
            A[q*3 + 1] = load_afrag(w_hh_l0 + (size_t)g*HH + quad*8);
            A[q*3 + 2] = load_afrag(w_hh_l0 + (size_t)g*HH + 32 + quad*8);
        }
        #pragma unroll
        for (int r = 0; r < 4; ++r) {
            const int j4 = js*16 + quad*4 + r;   // C row = quad*4 + reg
            bv0[r] = b_ih_l0[0*64 + j4] + b_hh_l0[0*64 + j4];
            bv1[r] = b_ih_l0[1*64 + j4] + b_hh_l0[1*64 + j4];
            bv2[r] = b_ih_l0[2*64 + j4] + b_hh_l0[2*64 + j4];
            bv3[r] = b_ih_l0[3*64 + j4] + b_hh_l0[3*64 + j4];
        }
    } else {
        #pragma unroll
        for (int q = 0; q < 4; ++q) {
            const int g = q*64 + js*16 + mrow;
            A[q*4 + 0] = load_afrag(w_ih_l1 + (size_t)g*HH + quad*8);
            A[q*4 + 1] = load_afrag(w_ih_l1 + (size_t)g*HH + 32 + quad*8);
            A[q*4 + 2] = load_afrag(w_hh_l1 + (size_t)g*HH + quad*8);
            A[q*4 + 3] = load_afrag(w_hh_l1 + (size_t)g*HH + 32 + quad*8);
        }
        #pragma unroll
        for (int r = 0; r < 4; ++r) {
            const int j4 = js*16 + quad*4 + r;
            bv0[r] = b_ih_l1[0*64 + j4] + b_hh_l1[0*64 + j4];
            bv1[r] = b_ih_l1[1*64 + j4] + b_hh_l1[1*64 + j4];
            bv2[r] = b_ih_l1[2*64 + j4] + b_hh_l1[2*64 + j4];
            bv3[r] = b_ih_l1[3*64 + j4] + b_hh_l1[3*64 + j4];
        }
    }

    // per-lane LDS offsets (f16 units, within a slot)
    const int roff = (bb*4 + quad)*8;
    const int cw   = (isL1 ? 1 : 3) + (jj >> 5);
    const int woff = ((cw*4 + bb)*4 + ((jj & 31) >> 3))*8 + (jj & 7);

    // x stager (wave 0): lane -> (batch = lane>>4, k-pair = lane&15)
    const float* xg = x + (size_t)(bbase + (lane >> 4)) * (TT*DD) + (lane & 15)*2;
    const int sdw = ((lane >> 4)*4 + ((lane & 15) >> 2))*4 + ((lane & 15) & 3);
    float2 xv1 = {0.f, 0.f}, xv2 = {0.f, 0.f};

    __syncthreads();   // zero-init visible
    if (wave == 0) {
        float2 v0 = *(const float2*)xg;                       // x(0) -> slot 0
        ((int*)(buf + 0*640))[sdw] = __builtin_bit_cast(int, pk(v0.x, v0.y));
        float2 v1 = *(const float2*)(xg + DD);                // x(1) -> slot 1
        ((int*)(buf + 1*640))[sdw] = __builtin_bit_cast(int, pk(v1.x, v1.y));
        xv1 = *(const float2*)(xg + 2*DD);                    // x(2)
        xv2 = *(const float2*)(xg + 3*DD);                    // x(3)
    }
    __syncthreads();

    // carried partial accumulators; prologue builds Ca = bias + x(0)-part (L1)
    f32x4 Ca0 = bv0, Ca1 = bv1, Ca2 = bv2, Ca3 = bv3;
    f32x4 Cb0 = bv0, Cb1 = bv1, Cb2 = bv2, Cb3 = bv3;
    if (isL1) {
        f16x8 B0 = *(const f16x8*)(buf + 0*640 + roff);
        Ca0 = MFMA16(A[0], B0, bv0);
        Ca1 = MFMA16(A[3], B0, bv1);
        Ca2 = MFMA16(A[6], B0, bv2);
        Ca3 = MFMA16(A[9], B0, bv3);
    }

    const bool s0 = (rsel & 1) != 0;
    const bool s1 = (rsel & 2) != 0;
    float cst = 0.0f;

#define ACT_WRITE(SLOT, C0_, C1_, C2_, C3_)                                   \
    {   float Si = pick4(C0_, s0, s1);   /* bias already in C */              \
        float Sf = pick4(C1_, s0, s1);                                        \
        float Sg = pick4(C2_, s0, s1);                                        \
        float So = pick4(C3_, s0, s1);                                        \
        float ii = fsig(Si), ff = fsig(Sf), oo = fsig(So);                    \
        float gg = ftanh(Sg);                                                 \
        cst = ff * cst + ii * gg;                                             \
        float hv = oo * ftanh(cst);                                           \
        buf[(SLOT)*640 + woff] = (__fp16)hv;                                  \
    }

#define STEP(K, P0,P1,P2,P3, Q0,Q1,Q2,Q3)                                     \
    {   const int t = tb + (K);                                               \
        if (wave == 0 && (t + 2 < TT)) {      /* stage x(t+2), issue x(t+4) */\
            ((int*)(buf + (((K)+2)&3)*640))[sdw] =                            \
                __builtin_bit_cast(int, pk(xv1.x, xv1.y));                    \
            xv1 = xv2;                                                        \
            const int tl = (t + 4 < TT) ? (t + 4) : (TT - 1);                 \
            xv2 = *(const float2*)(xg + (size_t)tl*DD);                       \
        }                                                                     \
        if (isL1) {                                                           \
            if (t < TT) {                     /* POST: += W_hh*h1(t-1), act */\
                const __fp16* bp = buf + (((K)-1)&3)*640;                     \
                f16x8 B1 = *(const f16x8*)(bp + 128 + roff);                  \
                f16x8 B2 = *(const f16x8*)(bp + 256 + roff);                  \
                P0 = MFMA16(A[1],  B1, P0); P0 = MFMA16(A[2],  B2, P0);       \
                P1 = MFMA16(A[4],  B1, P1); P1 = MFMA16(A[5],  B2, P1);       \
                P2 = MFMA16(A[7],  B1, P2); P2 = MFMA16(A[8],  B2, P2);       \
                P3 = MFMA16(A[10], B1, P3); P3 = MFMA16(A[11], B2, P3);       \
                ACT_WRITE((K)&3, P0, P1, P2, P3);                             \
            }                                                                 \
            if (t < TT - 1) {                 /* PRE: bias + W_ih*x(t+1) */   \
                f16x8 B0 = *(const f16x8*)(buf + (((K)+1)&3)*640 + roff);     \
                Q0 = MFMA16(A[0], B0, bv0);                                   \
                Q1 = MFMA16(A[3], B0, bv1);                                   \
                Q2 = MFMA16(A[6], B0, bv2);                                   \
                Q3 = MFMA16(A[9], B0, bv3);                                   \
            }                                                                 \
        } else {                                                              \
            if (t >= 2 && t <= TT + 1) {      /* POST: += W_hh*h2(t-3), act */\
                const __fp16* bp = buf + (((K)-3)&3)*640;                     \
                f16x8 B3 = *(const f16x8*)(bp + 384 + roff);                  \
                f16x8 B4 = *(const f16x8*)(bp + 512 + roff);                  \
                P0 = MFMA16(A[2],  B3, P0); P0 = MFMA16(A[3],  B4, P0);       \
                P1 = MFMA16(A[6],  B3, P1); P1 = MFMA16(A[7],  B4, P1);       \
                P2 = MFMA16(A[10], B3, P2); P2 = MFMA16(A[11], B4, P2);       \
                P3 = MFMA16(A[14], B3, P3); P3 = MFMA16(A[15], B4, P3);       \
                ACT_WRITE(((K)-2)&3, P0, P1, P2, P3);   /* h2(t-2) */         \
            }                                                                 \
            if (t >= 1 && t <= TT) {          /* PRE: bias + W_ih*h1(t-1) */  \
                const __fp16* bp = buf + (((K)-1)&3)*640;                     \
                f16x8 B1 = *(const f16x8*)(bp + 128 + roff);                  \
                f16x8 B2 = *(const f16x8*)(bp + 256 + roff);                  \
                Q0 = MFMA16(A[0],  B1, bv0); Q0 = MFMA16(A[1],  B2, Q0);      \
                Q1 = MFMA16(A[4],  B1, bv1); Q1 = MFMA16(A[5],  B2, Q1);      \
                Q2 = MFMA16(A[8],  B1, bv2); Q2 = MFMA16(A[9],  B2, Q2);      \
                Q3 = MFMA16(A[12], B1, bv3); Q3 = MFMA16(A[13], B2, Q3);      \
            }                                                                 \
        }                                                                     \
        __syncthreads();                                                      \
    }

    for (int tb = 0; tb < TT + 4; tb += 4) {   // t = 0 .. TT+3 (last 2 idle)
        STEP(0, Ca0,Ca1,Ca2,Ca3, Cb0,Cb1,Cb2,Cb3)
        STEP(1, Cb0,Cb1,Cb2,Cb3, Ca0,Ca1,Ca2,Ca3)
        STEP(2, Ca0,Ca1,Ca2,Ca3, Cb0,Cb1,Cb2,Cb3)
        STEP(3, Cb0,Cb1,Cb2,Cb3, Ca0,Ca1,Ca2,Ca3)
    }

#undef STEP
#undef ACT_WRITE

    // h2(TT-1) written at iter TT+1 into slot (TT-1)&3 = 3. FC + sigmoid.
    if (wave == 0) {
        const int jg = lane >> 2;   // 0..15
        float s = 0.f;
        #pragma unroll
        for (int u2 = 0; u2 < 4; ++u2) {
            const int j = jg*4 + u2;
            float hval = (float)buf[3*640 +
                (((3 + (j >> 5))*4 + bb)*4 + ((j & 31) >> 3))*8 + (j & 7)];
            s += hval * w_fc[j];
        }
        s += __shfl_xor(s, 4);
        s += __shfl_xor(s, 8);
        s += __shfl_xor(s, 16);
        s += __shfl_xor(s, 32);
        if (lane < 4) out[bbase + lane] = fsig(s + b_fc[0]);
    }
}

extern "C" void kernel_launch(void* const* d_in, const int* in_sizes, int n_in,
                              void* d_out, int out_size, void* d_ws, size_t ws_size,
                              hipStream_t stream) {
    lstm2_b4<<<dim3(64), dim3(512), 0, stream>>>(
        (const float*)d_in[0],
        (const float*)d_in[1], (const float*)d_in[2],
        (const float*)d_in[3], (const float*)d_in[4],
        (const float*)d_in[5], (const float*)d_in[6],
        (const float*)d_in[7], (const float*)d_in[8],
        (const float*)d_in[9], (const float*)d_in[10],
        (float*)d_out);
}